// Round 3
// baseline (302.793 us; speedup 1.0000x reference)
//
#include <hip/hip_runtime.h>

#define BB 512
#define TT 512
#define NN 64

__device__ __forceinline__ float readlane_f(float v, int lane) {
    return __int_as_float(__builtin_amdgcn_readlane(__float_as_int(v), lane));
}

// R3 lesson: 64x (v_readlane->SGPR, v_fma reads SGPR) pairs serialize on the
// VALU-writes-SGPR hazard (~10 cyc/pair ~= the measured 695 cyc/step; the
// allocator recycles few SGPRs so batching never happens). Fix: broadcast p
// through LDS -- 1 ds_write_b32 + 16 uniform-address ds_read_b128 (HW
// broadcast, conflict-free, immediate offsets). FMAs are VGPRxVGPR, zero
// SGPR hazards. Single wave => LDS pipe in-order, NO barrier needed.
// Also: stale-max trick -- m for step t is readlane(alpha_{t-1}, 0), issued
// during the previous dot => the readlane hazard is off the critical path.
// (logsumexp is exact under any bounded shift; |alpha - m| < ~30.)

#define DOTG(g, Ev) { \
    const float4 P = pl4[g]; \
    s0 = fmaf(P.x, Ev.x, s0); \
    s1 = fmaf(P.y, Ev.y, s1); \
    s2 = fmaf(P.z, Ev.z, s2); \
    s3 = fmaf(P.w, Ev.w, s3); }

__global__ __launch_bounds__(64, 1) void crf_kernel(
    const float* __restrict__ inputs,   // B*T*N fp32
    const float* __restrict__ trans,    // N*N fp32
    const int*   __restrict__ tags,     // B*T
    const int*   __restrict__ lens,     // B
    float*       __restrict__ out)      // [0,512) ll, [512,4608) trans copy
{
    const int b = blockIdx.x;
    const int j = threadIdx.x;          // 0..63

    // pass-through output: transition_params (4096 floats over first 64 blocks)
    if (b < 64) out[BB + b * 64 + j] = trans[b * 64 + j];

    const int L    = lens[b];
    const int last = (L - 1) > 0 ? (L - 1) : 0;

    const float* inb  = inputs + (size_t)b * TT * NN;
    const int*   tagb = tags + (size_t)b * TT;

    // ---- sequence score: unary (t < L) + binary (t+1 < L), 64 lanes x 8 ----
    float sc = 0.f;
    #pragma unroll
    for (int k = 0; k < 8; ++k) {
        const int t  = k * 64 + j;
        const int tg = tagb[t];
        if (t < L) sc += inb[t * NN + tg];
        if (t + 1 < L) sc += trans[tg * NN + tagb[t + 1]];   // L<=511 => safe
    }
    #pragma unroll
    for (int x = 32; x >= 1; x >>= 1) sc += __shfl_xor(sc, x, 64);

    // ---- E column j: E[i][j] = exp(trans[i][j]), 64 floats in named VGPRs ----
    float4 E0, E1, E2, E3, E4, E5, E6, E7, E8, E9, E10, E11, E12, E13, E14, E15;
#define LDE(Ev, g) \
    Ev.x = __expf(trans[(4 * (g) + 0) * NN + j]); \
    Ev.y = __expf(trans[(4 * (g) + 1) * NN + j]); \
    Ev.z = __expf(trans[(4 * (g) + 2) * NN + j]); \
    Ev.w = __expf(trans[(4 * (g) + 3) * NN + j]);
    LDE(E0, 0)   LDE(E1, 1)   LDE(E2, 2)   LDE(E3, 3)
    LDE(E4, 4)   LDE(E5, 5)   LDE(E6, 6)   LDE(E7, 7)
    LDE(E8, 8)   LDE(E9, 9)   LDE(E10, 10) LDE(E11, 11)
    LDE(E12, 12) LDE(E13, 13) LDE(E14, 14) LDE(E15, 15)
#undef LDE

    // p-broadcast buffer: 256 B LDS, single wave -> no barriers ever.
    __shared__ __align__(16) float plds[NN];
    const float4* pl4 = (const float4*)plds;

    float alpha = inb[j];                    // t = 0
    float m_sh  = readlane_f(alpha, 0);      // shift for first step (exact)

    // emit double-buffer: chunk A computes while chunk B loads, stride 32.
    float4 pA0, pA1, pA2, pA3, pB0, pB1, pB2, pB3;

#define LD(vec, comp, tt) { const int tc_ = (tt) <= last ? (tt) : last; \
                            vec.comp = inb[tc_ * NN + j]; }
#define LOADCHUNK(v0, v1, v2, v3, base) \
    LD(v0, x, (base) + 0)  LD(v0, y, (base) + 1)  LD(v0, z, (base) + 2)  LD(v0, w, (base) + 3)  \
    LD(v1, x, (base) + 4)  LD(v1, y, (base) + 5)  LD(v1, z, (base) + 6)  LD(v1, w, (base) + 7)  \
    LD(v2, x, (base) + 8)  LD(v2, y, (base) + 9)  LD(v2, z, (base) + 10) LD(v2, w, (base) + 11) \
    LD(v3, x, (base) + 12) LD(v3, y, (base) + 13) LD(v3, z, (base) + 14) LD(v3, w, (base) + 15)

#define STEP(tc_, EM) { \
    const float mu = m_sh; \
    const float p  = __expf(alpha - mu); \
    plds[j] = p; \
    m_sh = readlane_f(alpha, 0);  /* stale m for NEXT step; hidden under dot */ \
    float s0, s1, s2, s3; \
    { const float4 P = pl4[0]; \
      s0 = P.x * E0.x; s1 = P.y * E0.y; s2 = P.z * E0.z; s3 = P.w * E0.w; } \
    DOTG(1, E1)   DOTG(2, E2)   DOTG(3, E3) \
    DOTG(4, E4)   DOTG(5, E5)   DOTG(6, E6)   DOTG(7, E7) \
    DOTG(8, E8)   DOTG(9, E9)   DOTG(10, E10) DOTG(11, E11) \
    DOTG(12, E12) DOTG(13, E13) DOTG(14, E14) DOTG(15, E15) \
    const float s = (s0 + s1) + (s2 + s3); \
    if ((tc_) <= last) alpha = ((EM) + mu) + __logf(s); \
}

    LOADCHUNK(pA0, pA1, pA2, pA3, 1)

    for (int t0 = 1; t0 <= last; t0 += 32) {
        LOADCHUNK(pB0, pB1, pB2, pB3, t0 + 16)
        STEP(t0 + 0,  pA0.x) STEP(t0 + 1,  pA0.y) STEP(t0 + 2,  pA0.z) STEP(t0 + 3,  pA0.w)
        STEP(t0 + 4,  pA1.x) STEP(t0 + 5,  pA1.y) STEP(t0 + 6,  pA1.z) STEP(t0 + 7,  pA1.w)
        STEP(t0 + 8,  pA2.x) STEP(t0 + 9,  pA2.y) STEP(t0 + 10, pA2.z) STEP(t0 + 11, pA2.w)
        STEP(t0 + 12, pA3.x) STEP(t0 + 13, pA3.y) STEP(t0 + 14, pA3.z) STEP(t0 + 15, pA3.w)
        LOADCHUNK(pA0, pA1, pA2, pA3, t0 + 32)
        STEP(t0 + 16, pB0.x) STEP(t0 + 17, pB0.y) STEP(t0 + 18, pB0.z) STEP(t0 + 19, pB0.w)
        STEP(t0 + 20, pB1.x) STEP(t0 + 21, pB1.y) STEP(t0 + 22, pB1.z) STEP(t0 + 23, pB1.w)
        STEP(t0 + 24, pB2.x) STEP(t0 + 25, pB2.y) STEP(t0 + 26, pB2.z) STEP(t0 + 27, pB2.w)
        STEP(t0 + 28, pB3.x) STEP(t0 + 29, pB3.y) STEP(t0 + 30, pB3.z) STEP(t0 + 31, pB3.w)
    }
#undef STEP
#undef LOADCHUNK
#undef LD

    // ---- log_norm = logsumexp_j(alpha) ----
    float mm = alpha;
    #pragma unroll
    for (int x = 32; x >= 1; x >>= 1) mm = fmaxf(mm, __shfl_xor(mm, x, 64));
    float e = __expf(alpha - mm);
    #pragma unroll
    for (int x = 32; x >= 1; x >>= 1) e += __shfl_xor(e, x, 64);
    if (j == 0) out[b] = sc - (mm + __logf(e));
}

extern "C" void kernel_launch(void* const* d_in, const int* in_sizes, int n_in,
                              void* d_out, int out_size, void* d_ws, size_t ws_size,
                              hipStream_t stream) {
    const float* inputs = (const float*)d_in[0];
    const float* trans  = (const float*)d_in[1];
    const int*   tags   = (const int*)d_in[2];
    const int*   lens   = (const int*)d_in[3];
    float*       out    = (float*)d_out;

    crf_kernel<<<dim3(BB), dim3(64), 0, stream>>>(inputs, trans, tags, lens, out);
}

// Round 4
// 229.640 us; speedup vs baseline: 1.3186x; 1.3186x over previous
//
#include <hip/hip_runtime.h>

#define BB 512
#define TT 512
#define NN 64

__device__ __forceinline__ float readlane_f(float v, int lane) {
    return __int_as_float(__builtin_amdgcn_readlane(__float_as_int(v), lane));
}

// R4 design notes:
//  - R1/R2 both showed VGPR_Count=56 => E (64 floats/lane) was NEVER
//    register-resident (scratch reload or exp-remat per step), explaining
//    ~415 stall cyc/step over the ~280-cyc issue floor.
//  - R3's LDS p-broadcast put a ds round-trip ON the serial chain (+375).
//  - Fix: E in LDS (off-chain, LGKM pipe overlaps VALU; reads independent
//    of p so they issue under the exp), XOR-swizzled for conflict-free
//    column reads; p broadcast by BATCHED v_readlane into 16 DISTINCT
//    "=s" SGPRs per group (no single-SGPR write->read recycling).
//  - Keep stale-max (R3, absmax 0.0) and emit double-buffer prefetch.

#define S2(x) #x
#define S1(x) S2(x)
#define RL(o, l) "v_readlane_b32 %" S1(o) ", %16, " S1(l) "\n\t"

// 16 p-broadcasts (lanes (G)*16+0..15) -> r0..r15, then 16 fmas against
// E rows 16G..16G+15 read from swizzled LDS as 4x ds_read_b128.
#define GRP(G) { \
    const float4 Fa = ET4[jb + ((4 * (G) + 0) ^ jx)]; \
    const float4 Fb = ET4[jb + ((4 * (G) + 1) ^ jx)]; \
    const float4 Fc = ET4[jb + ((4 * (G) + 2) ^ jx)]; \
    const float4 Fd = ET4[jb + ((4 * (G) + 3) ^ jx)]; \
    float r0, r1, r2, r3, r4, r5, r6, r7, r8, r9, r10, r11, r12, r13, r14, r15; \
    asm(RL(0,  (G)*16+0)  RL(1,  (G)*16+1)  RL(2,  (G)*16+2)  RL(3,  (G)*16+3)  \
        RL(4,  (G)*16+4)  RL(5,  (G)*16+5)  RL(6,  (G)*16+6)  RL(7,  (G)*16+7)  \
        RL(8,  (G)*16+8)  RL(9,  (G)*16+9)  RL(10, (G)*16+10) RL(11, (G)*16+11) \
        RL(12, (G)*16+12) RL(13, (G)*16+13) RL(14, (G)*16+14) RL(15, (G)*16+15) \
        : "=s"(r0), "=s"(r1), "=s"(r2),  "=s"(r3),  "=s"(r4),  "=s"(r5),  "=s"(r6),  "=s"(r7), \
          "=s"(r8), "=s"(r9), "=s"(r10), "=s"(r11), "=s"(r12), "=s"(r13), "=s"(r14), "=s"(r15) \
        : "v"(p)); \
    s0 = fmaf(r0,  Fa.x, s0); s1 = fmaf(r1,  Fa.y, s1); \
    s2 = fmaf(r2,  Fa.z, s2); s3 = fmaf(r3,  Fa.w, s3); \
    s0 = fmaf(r4,  Fb.x, s0); s1 = fmaf(r5,  Fb.y, s1); \
    s2 = fmaf(r6,  Fb.z, s2); s3 = fmaf(r7,  Fb.w, s3); \
    s0 = fmaf(r8,  Fc.x, s0); s1 = fmaf(r9,  Fc.y, s1); \
    s2 = fmaf(r10, Fc.z, s2); s3 = fmaf(r11, Fc.w, s3); \
    s0 = fmaf(r12, Fd.x, s0); s1 = fmaf(r13, Fd.y, s1); \
    s2 = fmaf(r14, Fd.z, s2); s3 = fmaf(r15, Fd.w, s3); \
}

__global__ __launch_bounds__(64, 1) void crf_kernel(
    const float* __restrict__ inputs,   // B*T*N fp32
    const float* __restrict__ trans,    // N*N fp32
    const int*   __restrict__ tags,     // B*T
    const int*   __restrict__ lens,     // B
    float*       __restrict__ out)      // [0,512) ll, [512,4608) trans copy
{
    const int b = blockIdx.x;
    const int j = threadIdx.x;          // 0..63

    // pass-through output: transition_params (4096 floats over first 64 blocks)
    if (b < 64) out[BB + b * 64 + j] = trans[b * 64 + j];

    const int L    = lens[b];
    const int last = (L - 1) > 0 ? (L - 1) : 0;

    const float* inb  = inputs + (size_t)b * TT * NN;
    const int*   tagb = tags + (size_t)b * TT;

    // ---- sequence score: unary (t < L) + binary (t+1 < L), 64 lanes x 8 ----
    float sc = 0.f;
    #pragma unroll
    for (int k = 0; k < 8; ++k) {
        const int t  = k * 64 + j;
        const int tg = tagb[t];
        if (t < L) sc += inb[t * NN + tg];
        if (t + 1 < L) sc += trans[tg * NN + tagb[t + 1]];   // L<=511 => safe
    }
    #pragma unroll
    for (int x = 32; x >= 1; x >>= 1) sc += __shfl_xor(sc, x, 64);

    // ---- E^T in LDS, XOR-swizzled: lane j's column j is 16 float4 slots,
    //      group g stored at slot (g ^ (j&15)) so a same-g read across the
    //      wave spreads over all banks (<=2 lanes/bank = free). 16 KB. ----
    __shared__ __align__(16) float4 ET4[NN * 16];
    const int jb = j * 16;
    const int jx = j & 15;
    for (int g = 0; g < 16; ++g) {
        float4 v;
        v.x = __expf(trans[(4 * g + 0) * NN + j]);
        v.y = __expf(trans[(4 * g + 1) * NN + j]);
        v.z = __expf(trans[(4 * g + 2) * NN + j]);
        v.w = __expf(trans[(4 * g + 3) * NN + j]);
        ET4[jb + (g ^ jx)] = v;
    }
    // single wave: LDS pipe is in-order, no barrier needed.

    float alpha = inb[j];                    // t = 0
    float m_sh  = readlane_f(alpha, 0);      // shift for first step (exact)

    // emit double-buffer: chunk A computes while chunk B loads, stride 32.
    float4 pA0, pA1, pA2, pA3, pB0, pB1, pB2, pB3;

#define LD(vec, comp, tt) { const int tc_ = (tt) <= last ? (tt) : last; \
                            vec.comp = inb[tc_ * NN + j]; }
#define LOADCHUNK(v0, v1, v2, v3, base) \
    LD(v0, x, (base) + 0)  LD(v0, y, (base) + 1)  LD(v0, z, (base) + 2)  LD(v0, w, (base) + 3)  \
    LD(v1, x, (base) + 4)  LD(v1, y, (base) + 5)  LD(v1, z, (base) + 6)  LD(v1, w, (base) + 7)  \
    LD(v2, x, (base) + 8)  LD(v2, y, (base) + 9)  LD(v2, z, (base) + 10) LD(v2, w, (base) + 11) \
    LD(v3, x, (base) + 12) LD(v3, y, (base) + 13) LD(v3, z, (base) + 14) LD(v3, w, (base) + 15)

#define STEP(tc_, EM) { \
    const float mu = m_sh; \
    const float p  = __expf(alpha - mu); \
    m_sh = readlane_f(alpha, 0);  /* stale shift for NEXT step; off chain */ \
    float s0 = 0.f, s1 = 0.f, s2 = 0.f, s3 = 0.f; \
    GRP(0) GRP(1) GRP(2) GRP(3) \
    const float s = (s0 + s1) + (s2 + s3); \
    if ((tc_) <= last) alpha = ((EM) + mu) + __logf(s); \
}

    LOADCHUNK(pA0, pA1, pA2, pA3, 1)

    for (int t0 = 1; t0 <= last; t0 += 32) {
        LOADCHUNK(pB0, pB1, pB2, pB3, t0 + 16)
        STEP(t0 + 0,  pA0.x) STEP(t0 + 1,  pA0.y) STEP(t0 + 2,  pA0.z) STEP(t0 + 3,  pA0.w)
        STEP(t0 + 4,  pA1.x) STEP(t0 + 5,  pA1.y) STEP(t0 + 6,  pA1.z) STEP(t0 + 7,  pA1.w)
        STEP(t0 + 8,  pA2.x) STEP(t0 + 9,  pA2.y) STEP(t0 + 10, pA2.z) STEP(t0 + 11, pA2.w)
        STEP(t0 + 12, pA3.x) STEP(t0 + 13, pA3.y) STEP(t0 + 14, pA3.z) STEP(t0 + 15, pA3.w)
        LOADCHUNK(pA0, pA1, pA2, pA3, t0 + 32)
        STEP(t0 + 16, pB0.x) STEP(t0 + 17, pB0.y) STEP(t0 + 18, pB0.z) STEP(t0 + 19, pB0.w)
        STEP(t0 + 20, pB1.x) STEP(t0 + 21, pB1.y) STEP(t0 + 22, pB1.z) STEP(t0 + 23, pB1.w)
        STEP(t0 + 24, pB2.x) STEP(t0 + 25, pB2.y) STEP(t0 + 26, pB2.z) STEP(t0 + 27, pB2.w)
        STEP(t0 + 28, pB3.x) STEP(t0 + 29, pB3.y) STEP(t0 + 30, pB3.z) STEP(t0 + 31, pB3.w)
    }
#undef STEP
#undef LOADCHUNK
#undef LD

    // ---- log_norm = logsumexp_j(alpha) ----
    float mm = alpha;
    #pragma unroll
    for (int x = 32; x >= 1; x >>= 1) mm = fmaxf(mm, __shfl_xor(mm, x, 64));
    float e = __expf(alpha - mm);
    #pragma unroll
    for (int x = 32; x >= 1; x >>= 1) e += __shfl_xor(e, x, 64);
    if (j == 0) out[b] = sc - (mm + __logf(e));
}

extern "C" void kernel_launch(void* const* d_in, const int* in_sizes, int n_in,
                              void* d_out, int out_size, void* d_ws, size_t ws_size,
                              hipStream_t stream) {
    const float* inputs = (const float*)d_in[0];
    const float* trans  = (const float*)d_in[1];
    const int*   tags   = (const int*)d_in[2];
    const int*   lens   = (const int*)d_in[3];
    float*       out    = (float*)d_out;

    crf_kernel<<<dim3(BB), dim3(64), 0, stream>>>(inputs, trans, tags, lens, out);
}